// Round 1
// baseline (698.906 us; speedup 1.0000x reference)
//
#include <hip/hip_runtime.h>

#define NA 131072
#define NC 8
#define NK 2048
#define CAP 8192
#define NBMAX (NK / 64)   // 32 blocks of 64 bits per mask row
#define CONF 0.99f
#define IOUT 0.5f
#define IMGW 320.0f
#define IMGH 256.0f

// ---------------- ws layout (bytes) ----------------
// boxes  : NA*4 floats            @ 0        (2,097,152)
// counts : NC ints                @ 2097152  (64, padded)
// vkey   : NC*CAP u64             @ 2097216  (524,288)
// sbox   : NC*NK*4 floats         @ 2621504  (262,144)
// sscore : NC*NK floats           @ 2883648  (65,536)
// masks  : NC*NK*NBMAX u64        @ 2949184  (4,194,304)
// total ~ 7.15 MB

__global__ void k_init(float* __restrict__ out, int out_n, int* __restrict__ counts) {
    int i = blockIdx.x * blockDim.x + threadIdx.x;
    if (i < out_n) out[i] = 0.0f;
    if (i < NC) counts[i] = 0;
}

__global__ void k_decode(const float* __restrict__ cls,
                         const float* __restrict__ reg,
                         const float* __restrict__ anc,
                         float* __restrict__ boxes,
                         int* __restrict__ counts,
                         unsigned long long* __restrict__ vkey) {
#pragma clang fp contract(off)
    int a = blockIdx.x * blockDim.x + threadIdx.x;
    if (a >= NA) return;
    float a0 = anc[a * 4 + 0], a1 = anc[a * 4 + 1];
    float a2 = anc[a * 4 + 2], a3 = anc[a * 4 + 3];
    float wa = a2 - a0, ha = a3 - a1;
    float cxa = a0 + 0.5f * wa, cya = a1 + 0.5f * ha;
    float dx = reg[a * 4 + 0] * 0.1f;
    float dy = reg[a * 4 + 1] * 0.1f;
    float dw = reg[a * 4 + 2] * 0.2f;
    float dh = reg[a * 4 + 3] * 0.2f;
    float pcx = cxa + dx * wa;
    float pcy = cya + dy * ha;
    float pw = expf(dw) * wa;
    float ph = expf(dh) * ha;
    float x1 = fmaxf(pcx - 0.5f * pw, 0.0f);
    float y1 = fmaxf(pcy - 0.5f * ph, 0.0f);
    float x2 = fminf(pcx + 0.5f * pw, IMGW);
    float y2 = fminf(pcy + 0.5f * ph, IMGH);
    boxes[a * 4 + 0] = x1;
    boxes[a * 4 + 1] = y1;
    boxes[a * 4 + 2] = x2;
    boxes[a * 4 + 3] = y2;
    // compact above-threshold (class, anchor) entries with a unique sort key:
    // key = (score_bits << 32) | ~idx   -> desc key == (score desc, idx asc)
    for (int c = 0; c < NC; ++c) {
        float s = cls[a * NC + c];
        if (s > CONF) {
            int pos = atomicAdd(&counts[c], 1);
            if (pos < CAP) {
                unsigned int sb = __float_as_uint(s);
                vkey[c * CAP + pos] =
                    ((unsigned long long)sb << 32) | (unsigned int)(~a);
            }
        }
    }
}

__global__ void k_rank(const int* __restrict__ counts,
                       const unsigned long long* __restrict__ vkey,
                       const float* __restrict__ boxes,
                       float* __restrict__ sbox,
                       float* __restrict__ sscore) {
    int c = blockIdx.y;
    int e = blockIdx.x * blockDim.x + threadIdx.x;
    int M = min(counts[c], CAP);
    if (e >= M) return;
    const unsigned long long* kv = &vkey[c * CAP];
    unsigned long long ke = kv[e];
    int rank = 0;
    for (int j = 0; j < M; ++j) rank += (kv[j] > ke) ? 1 : 0;
    if (rank < NK) {
        int idx = (int)(~(unsigned int)ke);
        float s = __uint_as_float((unsigned int)(ke >> 32));
        int o = (c * NK + rank) * 4;
        sbox[o + 0] = boxes[idx * 4 + 0];
        sbox[o + 1] = boxes[idx * 4 + 1];
        sbox[o + 2] = boxes[idx * 4 + 2];
        sbox[o + 3] = boxes[idx * 4 + 3];
        sscore[c * NK + rank] = s;
    }
}

__global__ void k_mask(const int* __restrict__ counts,
                       const float* __restrict__ sbox,
                       unsigned long long* __restrict__ masks) {
#pragma clang fp contract(off)
    int c = blockIdx.y;
    int meff = min(min(counts[c], CAP), NK);
    int wave = threadIdx.x >> 6;   // 4 waves / block, one row each
    int lane = threadIdx.x & 63;
    int i = blockIdx.x * 4 + wave;
    if (i >= meff) return;
    const float* bi = &sbox[(c * NK + i) * 4];
    float ix1 = bi[0], iy1 = bi[1], ix2 = bi[2], iy2 = bi[3];
    float areai = fmaxf(ix2 - ix1, 0.0f) * fmaxf(iy2 - iy1, 0.0f);
    int nb = (meff + 63) >> 6;
    for (int b = 0; b < nb; ++b) {
        int j = (b << 6) + lane;
        bool pred = false;
        if (j < meff && j > i) {
            const float* bj = &sbox[(c * NK + j) * 4];
            float jx1 = bj[0], jy1 = bj[1], jx2 = bj[2], jy2 = bj[3];
            float areaj = fmaxf(jx2 - jx1, 0.0f) * fmaxf(jy2 - jy1, 0.0f);
            float xx1 = fmaxf(ix1, jx1), yy1 = fmaxf(iy1, jy1);
            float xx2 = fminf(ix2, jx2), yy2 = fminf(iy2, jy2);
            float inter = fmaxf(xx2 - xx1, 0.0f) * fmaxf(yy2 - yy1, 0.0f);
            float uni = (areai + areaj) - inter;
            float iou = inter / fmaxf(uni, 1e-8f);
            pred = iou > IOUT;
        }
        unsigned long long m = __ballot(pred);
        if (lane == 0) masks[(c * NK + i) * NBMAX + b] = m;
    }
}

__global__ void k_merge(const int* __restrict__ counts,
                        const float* __restrict__ sbox,
                        const float* __restrict__ sscore,
                        const unsigned long long* __restrict__ masks,
                        float* __restrict__ out) {
    int c = blockIdx.x;
    int lane = threadIdx.x;   // 64 threads = 1 wave
    int meff = min(min(counts[c], CAP), NK);
    int nb = (meff + 63) >> 6;
    unsigned long long remv = 0ULL;
    for (int i = 0; i < meff; ++i) {
        int blk = i >> 6, bit = i & 63;
        unsigned long long rb = __shfl(remv, blk);
        if (!((rb >> bit) & 1ULL)) {
            // row i kept: absorb its suppression mask, emit output row
            if (lane < nb) remv |= masks[(c * NK + i) * NBMAX + lane];
            int row = c * NK + i;
            if (lane < 4) out[row * 6 + lane] = sbox[row * 4 + lane];
            else if (lane == 4) out[row * 6 + 4] = sscore[row];
            else if (lane == 5) out[row * 6 + 5] = (float)c;
        }
    }
}

extern "C" void kernel_launch(void* const* d_in, const int* in_sizes, int n_in,
                              void* d_out, int out_size, void* d_ws, size_t ws_size,
                              hipStream_t stream) {
    const float* cls = (const float*)d_in[0];   // [1, A, C]
    const float* reg = (const float*)d_in[1];   // [1, A, 4]
    const float* anc = (const float*)d_in[2];   // [1, A, 4]
    float* out = (float*)d_out;                 // [C*K, 6]

    char* ws = (char*)d_ws;
    float* boxes = (float*)(ws + 0);
    int* counts = (int*)(ws + 2097152);
    unsigned long long* vkey = (unsigned long long*)(ws + 2097216);
    float* sbox = (float*)(ws + 2621504);
    float* sscore = (float*)(ws + 2883648);
    unsigned long long* masks = (unsigned long long*)(ws + 2949184);

    k_init<<<(out_size + 255) / 256, 256, 0, stream>>>(out, out_size, counts);
    k_decode<<<(NA + 255) / 256, 256, 0, stream>>>(cls, reg, anc, boxes, counts, vkey);
    k_rank<<<dim3(CAP / 256, NC), 256, 0, stream>>>(counts, vkey, boxes, sbox, sscore);
    k_mask<<<dim3((NK + 3) / 4, NC), 256, 0, stream>>>(counts, sbox, masks);
    k_merge<<<NC, 64, 0, stream>>>(counts, sbox, sscore, masks, out);
}

// Round 2
// 485.967 us; speedup vs baseline: 1.4382x; 1.4382x over previous
//
#include <hip/hip_runtime.h>

#define NA 131072
#define NC 8
#define NK 2048
#define CAP 8192
#define CONF 0.99f
#define IOUT 0.5f
#define IMGW 320.0f
#define IMGH 256.0f

// ---------------- ws layout (bytes) ----------------
// boxes  : NA*4 floats            @ 0        (2,097,152)
// counts : NC ints                @ 2097152  (64, padded)
// vkey   : NC*CAP u64             @ 2097216  (524,288)
// sbox   : NC*NK*4 floats         @ 2621504  (262,144)
// sscore : NC*NK floats           @ 2883648  (65,536)
// total ~ 2.95 MB

__global__ void k_init(float* __restrict__ out, int out_n, int* __restrict__ counts) {
    int i = blockIdx.x * blockDim.x + threadIdx.x;
    if (i < out_n) out[i] = 0.0f;
    if (i < NC) counts[i] = 0;
}

__global__ void k_decode(const float* __restrict__ cls,
                         const float* __restrict__ reg,
                         const float* __restrict__ anc,
                         float* __restrict__ boxes,
                         int* __restrict__ counts,
                         unsigned long long* __restrict__ vkey) {
#pragma clang fp contract(off)
    int a = blockIdx.x * blockDim.x + threadIdx.x;
    if (a >= NA) return;
    float a0 = anc[a * 4 + 0], a1 = anc[a * 4 + 1];
    float a2 = anc[a * 4 + 2], a3 = anc[a * 4 + 3];
    float wa = a2 - a0, ha = a3 - a1;
    float cxa = a0 + 0.5f * wa, cya = a1 + 0.5f * ha;
    float dx = reg[a * 4 + 0] * 0.1f;
    float dy = reg[a * 4 + 1] * 0.1f;
    float dw = reg[a * 4 + 2] * 0.2f;
    float dh = reg[a * 4 + 3] * 0.2f;
    float pcx = cxa + dx * wa;
    float pcy = cya + dy * ha;
    float pw = expf(dw) * wa;
    float ph = expf(dh) * ha;
    float x1 = fmaxf(pcx - 0.5f * pw, 0.0f);
    float y1 = fmaxf(pcy - 0.5f * ph, 0.0f);
    float x2 = fminf(pcx + 0.5f * pw, IMGW);
    float y2 = fminf(pcy + 0.5f * ph, IMGH);
    boxes[a * 4 + 0] = x1;
    boxes[a * 4 + 1] = y1;
    boxes[a * 4 + 2] = x2;
    boxes[a * 4 + 3] = y2;
    // compact above-threshold (class, anchor) entries with a unique sort key:
    // key = (score_bits << 32) | ~idx   -> desc key == (score desc, idx asc)
    for (int c = 0; c < NC; ++c) {
        float s = cls[a * NC + c];
        if (s > CONF) {
            int pos = atomicAdd(&counts[c], 1);
            if (pos < CAP) {
                unsigned int sb = __float_as_uint(s);
                vkey[c * CAP + pos] =
                    ((unsigned long long)sb << 32) | (unsigned int)(~a);
            }
        }
    }
}

// one block (1024 threads) per class; keys staged in LDS, rank-by-count
__global__ __launch_bounds__(1024) void k_rank(const int* __restrict__ counts,
                                               const unsigned long long* __restrict__ vkey,
                                               const float* __restrict__ boxes,
                                               float* __restrict__ sbox,
                                               float* __restrict__ sscore) {
    __shared__ unsigned long long kv[CAP];   // 64 KB
    int c = blockIdx.x;
    int tid = threadIdx.x;
    int M = min(counts[c], CAP);
    for (int e = tid; e < M; e += 1024) kv[e] = vkey[c * CAP + e];
    __syncthreads();
    for (int e = tid; e < M; e += 1024) {
        unsigned long long ke = kv[e];
        int rank = 0;
        int j = 0;
        for (; j + 4 <= M; j += 4) {
            rank += (kv[j] > ke);
            rank += (kv[j + 1] > ke);
            rank += (kv[j + 2] > ke);
            rank += (kv[j + 3] > ke);
        }
        for (; j < M; ++j) rank += (kv[j] > ke);
        if (rank < NK) {
            int idx = (int)(~(unsigned int)ke);
            float s = __uint_as_float((unsigned int)(ke >> 32));
            int o = (c * NK + rank) * 4;
            sbox[o + 0] = boxes[idx * 4 + 0];
            sbox[o + 1] = boxes[idx * 4 + 1];
            sbox[o + 2] = boxes[idx * 4 + 2];
            sbox[o + 3] = boxes[idx * 4 + 3];
            sscore[c * NK + rank] = s;
        }
    }
}

// fused NMS (mask + greedy merge + output write), one block per class.
// 64-wide chunks: wave 0 runs intra-chunk greedy via shfl/ballot (registers),
// then all 16 waves suppress later rows against the chunk's kept boxes.
__global__ __launch_bounds__(1024) void k_nms(const int* __restrict__ counts,
                                              const float* __restrict__ sbox,
                                              const float* __restrict__ sscore,
                                              float* __restrict__ out) {
#pragma clang fp contract(off)
    __shared__ float bx[NK][4];          // 32 KB
    __shared__ float bar[NK];            // 8 KB
    __shared__ unsigned char sup[NK];    // 2 KB
    __shared__ int chunk_list[64];
    __shared__ int chunk_cnt;

    int c = blockIdx.x;
    int tid = threadIdx.x;
    int meff = min(min(counts[c], CAP), NK);

    // stage sorted boxes + areas, clear flags
    for (int r = tid; r < meff; r += 1024) {
        const float* p = &sbox[(c * NK + r) * 4];
        float x1 = p[0], y1 = p[1], x2 = p[2], y2 = p[3];
        bx[r][0] = x1; bx[r][1] = y1; bx[r][2] = x2; bx[r][3] = y2;
        bar[r] = fmaxf(x2 - x1, 0.0f) * fmaxf(y2 - y1, 0.0f);
        sup[r] = 0;
    }
    __syncthreads();

    // own rows (for apply phase), kept in registers
    int j0 = tid, j1 = tid + 1024;
    float o0x1 = 0, o0y1 = 0, o0x2 = 0, o0y2 = 0, o0a = 0;
    float o1x1 = 0, o1y1 = 0, o1x2 = 0, o1y2 = 0, o1a = 0;
    if (j0 < meff) { o0x1 = bx[j0][0]; o0y1 = bx[j0][1]; o0x2 = bx[j0][2]; o0y2 = bx[j0][3]; o0a = bar[j0]; }
    if (j1 < meff) { o1x1 = bx[j1][0]; o1y1 = bx[j1][1]; o1x2 = bx[j1][2]; o1y2 = bx[j1][3]; o1a = bar[j1]; }

    int nchunk = (meff + 63) >> 6;
    for (int t = 0; t < nchunk; ++t) {
        int base = t << 6;
        if (tid < 64) {   // wave 0: intra-chunk greedy
            int l = tid;
            int r = base + l;
            bool inr = r < meff;
            float x1 = 0, y1 = 0, x2 = 0, y2 = 0, ar = 0;
            if (inr) { x1 = bx[r][0]; y1 = bx[r][1]; x2 = bx[r][2]; y2 = bx[r][3]; ar = bar[r]; }
            bool valid = inr && (sup[r] == 0);
            unsigned long long live = __ballot(valid);
            for (int b = 0; b < 64; ++b) {
                if (!((live >> b) & 1ULL)) continue;
                float px1 = __shfl(x1, b);
                float py1 = __shfl(y1, b);
                float px2 = __shfl(x2, b);
                float py2 = __shfl(y2, b);
                float par = __shfl(ar, b);
                float xx1 = fmaxf(x1, px1), yy1 = fmaxf(y1, py1);
                float xx2 = fminf(x2, px2), yy2 = fminf(y2, py2);
                float inter = fmaxf(xx2 - xx1, 0.0f) * fmaxf(yy2 - yy1, 0.0f);
                float uni = (ar + par) - inter;
                float iou = inter / fmaxf(uni, 1e-8f);
                unsigned long long sm = __ballot((iou > IOUT) && (l > b));
                live &= ~sm;
            }
            bool keep = inr && ((live >> l) & 1ULL);
            if (valid && !keep) sup[r] = 1;
            if (keep) {
                int pos = __popcll(live & ((1ULL << l) - 1ULL));
                chunk_list[pos] = r;
            }
            if (l == 0) chunk_cnt = (int)__popcll(live);
        }
        __syncthreads();

        // apply phase: suppress rows after this chunk against kept boxes
        int cnt = chunk_cnt;
        int lim = base + 64;
        bool a0 = (j0 >= lim) && (j0 < meff) && (sup[j0] == 0);
        bool a1 = (j1 >= lim) && (j1 < meff) && (sup[j1] == 0);
        if (cnt > 0 && (a0 || a1)) {
            for (int k = 0; k < cnt; ++k) {
                int r = chunk_list[k];
                float px1 = bx[r][0], py1 = bx[r][1], px2 = bx[r][2], py2 = bx[r][3];
                float par = bar[r];
                if (a0) {
                    float xx1 = fmaxf(o0x1, px1), yy1 = fmaxf(o0y1, py1);
                    float xx2 = fminf(o0x2, px2), yy2 = fminf(o0y2, py2);
                    float inter = fmaxf(xx2 - xx1, 0.0f) * fmaxf(yy2 - yy1, 0.0f);
                    float uni = (o0a + par) - inter;
                    float iou = inter / fmaxf(uni, 1e-8f);
                    if (iou > IOUT) { sup[j0] = 1; a0 = false; }
                }
                if (a1) {
                    float xx1 = fmaxf(o1x1, px1), yy1 = fmaxf(o1y1, py1);
                    float xx2 = fminf(o1x2, px2), yy2 = fminf(o1y2, py2);
                    float inter = fmaxf(xx2 - xx1, 0.0f) * fmaxf(yy2 - yy1, 0.0f);
                    float uni = (o1a + par) - inter;
                    float iou = inter / fmaxf(uni, 1e-8f);
                    if (iou > IOUT) { sup[j1] = 1; a1 = false; }
                }
            }
        }
        __syncthreads();
    }

    // write kept rows (out pre-zeroed by k_init)
    for (int r = tid; r < meff; r += 1024) {
        if (!sup[r]) {
            int row = c * NK + r;
            out[row * 6 + 0] = bx[r][0];
            out[row * 6 + 1] = bx[r][1];
            out[row * 6 + 2] = bx[r][2];
            out[row * 6 + 3] = bx[r][3];
            out[row * 6 + 4] = sscore[row];
            out[row * 6 + 5] = (float)c;
        }
    }
}

extern "C" void kernel_launch(void* const* d_in, const int* in_sizes, int n_in,
                              void* d_out, int out_size, void* d_ws, size_t ws_size,
                              hipStream_t stream) {
    const float* cls = (const float*)d_in[0];   // [1, A, C]
    const float* reg = (const float*)d_in[1];   // [1, A, 4]
    const float* anc = (const float*)d_in[2];   // [1, A, 4]
    float* out = (float*)d_out;                 // [C*K, 6]

    char* ws = (char*)d_ws;
    float* boxes = (float*)(ws + 0);
    int* counts = (int*)(ws + 2097152);
    unsigned long long* vkey = (unsigned long long*)(ws + 2097216);
    float* sbox = (float*)(ws + 2621504);
    float* sscore = (float*)(ws + 2883648);

    k_init<<<(out_size + 255) / 256, 256, 0, stream>>>(out, out_size, counts);
    k_decode<<<(NA + 255) / 256, 256, 0, stream>>>(cls, reg, anc, boxes, counts, vkey);
    k_rank<<<NC, 1024, 0, stream>>>(counts, vkey, boxes, sbox, sscore);
    k_nms<<<NC, 1024, 0, stream>>>(counts, sbox, sscore, out);
}

// Round 3
// 433.849 us; speedup vs baseline: 1.6109x; 1.1201x over previous
//
#include <hip/hip_runtime.h>

#define NA 131072
#define NC 8
#define NK 2048
#define CAP 8192
#define CONF 0.99f
#define IOUT 0.5f
#define IMGW 320.0f
#define IMGH 256.0f

// ---------------- ws layout (bytes) ----------------
// boxes  : NA float4              @ 0        (2,097,152)
// counts : NC ints                @ 2097152  (64, padded)
// vkey   : NC*CAP u64             @ 2097216  (524,288)
// total ~ 2.62 MB

__global__ void k_init(int* __restrict__ counts) {
    if (threadIdx.x < NC) counts[threadIdx.x] = 0;
}

__global__ void k_decode(const float* __restrict__ cls,
                         const float4* __restrict__ reg,
                         const float4* __restrict__ anc,
                         float4* __restrict__ boxes,
                         int* __restrict__ counts,
                         unsigned long long* __restrict__ vkey) {
#pragma clang fp contract(off)
    int a = blockIdx.x * blockDim.x + threadIdx.x;   // grid exactly covers NA
    int lane = threadIdx.x & 63;
    float4 av = anc[a];
    float4 rv = reg[a];
    float wa = av.z - av.x, ha = av.w - av.y;
    float cxa = av.x + 0.5f * wa, cya = av.y + 0.5f * ha;
    float dx = rv.x * 0.1f, dy = rv.y * 0.1f;
    float dw = rv.z * 0.2f, dh = rv.w * 0.2f;
    float pcx = cxa + dx * wa, pcy = cya + dy * ha;
    float pw = expf(dw) * wa, ph = expf(dh) * ha;
    float4 b;
    b.x = fmaxf(pcx - 0.5f * pw, 0.0f);
    b.y = fmaxf(pcy - 0.5f * ph, 0.0f);
    b.z = fminf(pcx + 0.5f * pw, IMGW);
    b.w = fminf(pcy + 0.5f * ph, IMGH);
    boxes[a] = b;

    const float4* c4 = (const float4*)(cls + (size_t)a * NC);
    float4 s0 = c4[0], s1 = c4[1];
    float sc[8] = {s0.x, s0.y, s0.z, s0.w, s1.x, s1.y, s1.z, s1.w};
    #pragma unroll
    for (int c = 0; c < NC; ++c) {
        float s = sc[c];
        bool p = s > CONF;
        unsigned long long m = __ballot(p);
        int cnt = __popcll(m);
        if (cnt) {
            int base = 0;
            if (lane == 0) base = atomicAdd(&counts[c], cnt);
            base = __shfl(base, 0);
            if (p) {
                int off = __popcll(m & ((1ULL << lane) - 1ULL));
                int pos = base + off;
                if (pos < CAP) {
                    vkey[c * CAP + pos] =
                        ((unsigned long long)__float_as_uint(s) << 32) |
                        (unsigned int)(~a);
                }
            }
        }
    }
}

// Fused rank (top-K by counting) + NMS, one block (1024 thr) per class.
// LDS: kv 64K + bx 32K + bar 8K + ssc 8K + sup 2K + intra 16K = 133 KB.
__global__ __launch_bounds__(1024) void k_rank_nms(
        const int* __restrict__ counts,
        const unsigned long long* __restrict__ vkey,
        const float4* __restrict__ boxes,
        float* __restrict__ out) {
#pragma clang fp contract(off)
    __shared__ unsigned long long kv[CAP];
    __shared__ float4 bx[NK];
    __shared__ float bar[NK];
    __shared__ float ssc[NK];
    __shared__ unsigned char sup[NK];
    __shared__ unsigned long long intra[NK];
    __shared__ unsigned long long kept_sh;

    int c = blockIdx.x;
    int tid = threadIdx.x;
    int lane = tid & 63;
    int wid = tid >> 6;

    int M = min(counts[c], CAP);
    int meff = min(M, NK);

    // ---- stage keys ----
    for (int e = tid; e < M; e += 1024) kv[e] = vkey[c * CAP + e];
    __syncthreads();

    // ---- rank by counting (unique keys -> exact sorted position) ----
    for (int e = tid; e < M; e += 1024) {
        unsigned long long ke = kv[e];
        int rank = 0;
        int j = 0;
        for (; j + 4 <= M; j += 4) {
            rank += (kv[j] > ke);
            rank += (kv[j + 1] > ke);
            rank += (kv[j + 2] > ke);
            rank += (kv[j + 3] > ke);
        }
        for (; j < M; ++j) rank += (kv[j] > ke);
        if (rank < NK) {
            int idx = (int)(~(unsigned int)ke);
            bx[rank] = boxes[idx];
            ssc[rank] = __uint_as_float((unsigned int)(ke >> 32));
        }
    }
    __syncthreads();

    // ---- areas + flags ----
    for (int r = tid; r < meff; r += 1024) {
        float4 b = bx[r];
        bar[r] = fmaxf(b.z - b.x, 0.0f) * fmaxf(b.w - b.y, 0.0f);
        sup[r] = 0;
    }
    __syncthreads();

    // ---- parallel intra-chunk 64x64 suppression bit-matrices ----
    for (int r = wid; r < meff; r += 16) {
        float4 bi = bx[r];
        float ai = bar[r];
        int col = (r & ~63) | lane;
        bool pred = false;
        if (col > r && col < meff) {
            float4 bj = bx[col];
            float aj = bar[col];
            float xx1 = fmaxf(bi.x, bj.x), yy1 = fmaxf(bi.y, bj.y);
            float xx2 = fminf(bi.z, bj.z), yy2 = fminf(bi.w, bj.w);
            float inter = fmaxf(xx2 - xx1, 0.0f) * fmaxf(yy2 - yy1, 0.0f);
            float uni = (ai + aj) - inter;
            pred = (inter / fmaxf(uni, 1e-8f)) > IOUT;
        }
        unsigned long long m = __ballot(pred);
        if (lane == 0) intra[r] = m;
    }
    __syncthreads();

    // ---- own rows for the apply phase (registers) ----
    int j0 = tid, j1 = tid + 1024;
    float4 ob0 = make_float4(0, 0, 0, 0), ob1 = make_float4(0, 0, 0, 0);
    float oa0 = 0, oa1 = 0;
    if (j0 < meff) { ob0 = bx[j0]; oa0 = bar[j0]; }
    if (j1 < meff) { ob1 = bx[j1]; oa1 = bar[j1]; }
    bool done0 = (j0 >= meff), done1 = (j1 >= meff);

    int nchunk = (meff + 63) >> 6;
    for (int t = 0; t < nchunk; ++t) {
        int base = t << 6;
        if (wid == 0) {
            // serial greedy on bitmasks only; iterations == kept count
            int r = base + lane;
            bool valid = (r < meff) && (sup[r] == 0);
            unsigned long long pending = __ballot(valid);
            unsigned long long mr = (r < meff) ? intra[r] : 0ULL;
            unsigned int mlo = (unsigned int)mr;
            unsigned int mhi = (unsigned int)(mr >> 32);
            unsigned long long kept = 0;
            while (pending) {
                int b = __ffsll(pending) - 1;
                kept |= 1ULL << b;
                unsigned int lo = (unsigned int)__builtin_amdgcn_readlane((int)mlo, b);
                unsigned int hi = (unsigned int)__builtin_amdgcn_readlane((int)mhi, b);
                unsigned long long sm =
                    (((unsigned long long)hi << 32) | lo) | (1ULL << b);
                pending &= ~sm;
            }
            if (valid && !((kept >> lane) & 1ULL)) sup[r] = 1;
            if (lane == 0) kept_sh = kept;
        }
        __syncthreads();

        unsigned long long kb = kept_sh;
        int lim = base + 64;
        if (!done0 && j0 < lim) done0 = true;   // own chunk now resolved
        if (!done1 && j1 < lim) done1 = true;
        if (kb && (!done0 || !done1)) {
            unsigned long long bits = kb;
            while (bits) {
                int b = __ffsll(bits) - 1;
                bits &= bits - 1;
                int r = base + b;
                float4 pb = bx[r];     // broadcast LDS read
                float pa = bar[r];
                if (!done0) {
                    float xx1 = fmaxf(ob0.x, pb.x), yy1 = fmaxf(ob0.y, pb.y);
                    float xx2 = fminf(ob0.z, pb.z), yy2 = fminf(ob0.w, pb.w);
                    float inter = fmaxf(xx2 - xx1, 0.0f) * fmaxf(yy2 - yy1, 0.0f);
                    float uni = (oa0 + pa) - inter;
                    if (inter / fmaxf(uni, 1e-8f) > IOUT) { sup[j0] = 1; done0 = true; }
                }
                if (!done1) {
                    float xx1 = fmaxf(ob1.x, pb.x), yy1 = fmaxf(ob1.y, pb.y);
                    float xx2 = fminf(ob1.z, pb.z), yy2 = fminf(ob1.w, pb.w);
                    float inter = fmaxf(xx2 - xx1, 0.0f) * fmaxf(yy2 - yy1, 0.0f);
                    float uni = (oa1 + pa) - inter;
                    if (inter / fmaxf(uni, 1e-8f) > IOUT) { sup[j1] = 1; done1 = true; }
                }
            }
        }
        __syncthreads();
    }

    // ---- write all NK rows for this class (kept -> data, else zeros) ----
    for (int r = tid; r < NK; r += 1024) {
        int row = c * NK + r;
        bool k = (r < meff) && (sup[r] == 0);
        float x1 = 0, y1 = 0, x2 = 0, y2 = 0, s = 0, cl = 0;
        if (k) {
            float4 b = bx[r];
            x1 = b.x; y1 = b.y; x2 = b.z; y2 = b.w;
            s = ssc[r]; cl = (float)c;
        }
        out[row * 6 + 0] = x1;
        out[row * 6 + 1] = y1;
        out[row * 6 + 2] = x2;
        out[row * 6 + 3] = y2;
        out[row * 6 + 4] = s;
        out[row * 6 + 5] = cl;
    }
}

extern "C" void kernel_launch(void* const* d_in, const int* in_sizes, int n_in,
                              void* d_out, int out_size, void* d_ws, size_t ws_size,
                              hipStream_t stream) {
    const float* cls = (const float*)d_in[0];   // [1, A, C]
    const float4* reg = (const float4*)d_in[1]; // [1, A, 4]
    const float4* anc = (const float4*)d_in[2]; // [1, A, 4]
    float* out = (float*)d_out;                 // [C*K, 6]

    char* ws = (char*)d_ws;
    float4* boxes = (float4*)(ws + 0);
    int* counts = (int*)(ws + 2097152);
    unsigned long long* vkey = (unsigned long long*)(ws + 2097216);

    k_init<<<1, 64, 0, stream>>>(counts);
    k_decode<<<NA / 256, 256, 0, stream>>>(cls, reg, anc, boxes, counts, vkey);
    k_rank_nms<<<NC, 1024, 0, stream>>>(counts, vkey, boxes, out);
}

// Round 4
// 350.296 us; speedup vs baseline: 1.9952x; 1.2385x over previous
//
#include <hip/hip_runtime.h>

#define NA 131072
#define NC 8
#define NK 2048
#define CAP 8192
#define CONF 0.99f
#define IOUT 0.5f
#define IMGW 320.0f
#define IMGH 256.0f
#define CSTRIDE 32   // ints between class counters (128 B -> separate cachelines)

typedef unsigned long long u64;

// ---------------- ws layout (bytes) ----------------
// counts : NC*CSTRIDE ints  @ 0     (1 KB)
// vkey   : NC*CAP u64       @ 1024  (512 KB)

__global__ void k_init(int* __restrict__ counts) {
    if (threadIdx.x < NC * CSTRIDE) counts[threadIdx.x] = 0;
}

// score scan + compaction into per-class key arrays.
// key = (score_bits << 32) | ~anchor  -> desc key == (score desc, idx asc)
__global__ __launch_bounds__(1024) void k_scan(const float* __restrict__ cls,
                                               int* __restrict__ counts,
                                               u64* __restrict__ vkey) {
    __shared__ int lcnt[NC];
    __shared__ int lbase[NC];
    int tid = threadIdx.x;
    int lane = tid & 63;
    int a = blockIdx.x * 1024 + tid;

    const float4* c4 = (const float4*)(cls + (size_t)a * NC);
    float4 s0 = c4[0], s1 = c4[1];
    float sc[8] = {s0.x, s0.y, s0.z, s0.w, s1.x, s1.y, s1.z, s1.w};

    if (tid < NC) lcnt[tid] = 0;
    __syncthreads();

    int wbase[NC], off[NC];
    bool hit[NC];
    #pragma unroll
    for (int c = 0; c < NC; ++c) {
        float s = sc[c];
        bool p = s > CONF;
        u64 m = __ballot(p);
        int cnt = __popcll(m);
        int wb = 0;
        if (cnt && lane == 0) wb = atomicAdd(&lcnt[c], cnt);
        wb = __shfl(wb, 0);
        wbase[c] = wb;
        hit[c] = p;
        off[c] = __popcll(m & ((1ULL << lane) - 1ULL));
    }
    __syncthreads();
    if (tid < NC) lbase[tid] = atomicAdd(&counts[tid * CSTRIDE], lcnt[tid]);
    __syncthreads();

    #pragma unroll
    for (int c = 0; c < NC; ++c) {
        if (hit[c]) {
            int pos = lbase[c] + wbase[c] + off[c];
            if (pos < CAP) {
                vkey[c * CAP + pos] =
                    ((u64)__float_as_uint(sc[c]) << 32) | (unsigned int)(~a);
            }
        }
    }
}

// Fused rank (register-tile counting) + lazy decode + NMS. One block / class.
__global__ __launch_bounds__(1024) void k_rank_nms(
        const int* __restrict__ counts,
        const u64* __restrict__ vkey,
        const float4* __restrict__ anc,
        const float4* __restrict__ reg,
        float* __restrict__ out) {
#pragma clang fp contract(off)
    __shared__ u64 kv[CAP];              // 64 KB
    __shared__ float4 bx[NK];            // 32 KB
    __shared__ float bar[NK];            // 8 KB
    __shared__ float ssc[NK];            // 8 KB
    __shared__ unsigned char sup[NK];    // 2 KB
    __shared__ u64 intra[NK];            // 16 KB
    __shared__ u64 kept_sh;

    int c = blockIdx.x;
    int tid = threadIdx.x;
    int lane = tid & 63;
    int wid = tid >> 6;

    int M = min(counts[c * CSTRIDE], CAP);
    int meff = min(M, NK);
    int Mr = (M + 63) & ~63;   // tile-padded key count

    // ---- stage keys (zero-pad to tile multiple), clear sup ----
    for (int e = tid; e < Mr; e += 1024) kv[e] = (e < M) ? vkey[c * CAP + e] : 0ULL;
    for (int r = tid; r < meff; r += 1024) sup[r] = 0;
    __syncthreads();

    // ---- rank by counting, register tiles + readlane broadcast ----
    int e0 = tid, e1 = tid + 1024;
    u64 ke0 = (e0 < M) ? kv[e0] : ~0ULL;
    u64 ke1 = (e1 < M) ? kv[e1] : ~0ULL;
    int r0 = 0, r1 = 0;
    if (__any(e0 < M)) {
        if (__any(e1 < M)) {
            for (int base = 0; base < Mr; base += 64) {
                u64 tile = kv[base + lane];
                unsigned tlo = (unsigned)tile, thi = (unsigned)(tile >> 32);
                #pragma unroll
                for (int b = 0; b < 64; ++b) {
                    unsigned lo = (unsigned)__builtin_amdgcn_readlane((int)tlo, b);
                    unsigned hi = (unsigned)__builtin_amdgcn_readlane((int)thi, b);
                    u64 key = ((u64)hi << 32) | lo;
                    r0 += (key > ke0);
                    r1 += (key > ke1);
                }
            }
        } else {
            for (int base = 0; base < Mr; base += 64) {
                u64 tile = kv[base + lane];
                unsigned tlo = (unsigned)tile, thi = (unsigned)(tile >> 32);
                #pragma unroll
                for (int b = 0; b < 64; ++b) {
                    unsigned lo = (unsigned)__builtin_amdgcn_readlane((int)tlo, b);
                    unsigned hi = (unsigned)__builtin_amdgcn_readlane((int)thi, b);
                    u64 key = ((u64)hi << 32) | lo;
                    r0 += (key > ke0);
                }
            }
        }
    }

    // ---- lazy decode of the selected anchors into sorted slots ----
    #pragma unroll
    for (int pass = 0; pass < 2; ++pass) {
        int e = pass ? e1 : e0;
        int rk = pass ? r1 : r0;
        u64 ke = pass ? ke1 : ke0;
        if (e < M && rk < NK) {
            int idx = (int)(~(unsigned int)ke);
            float4 av = anc[idx];
            float4 rv = reg[idx];
            float wa = av.z - av.x, ha = av.w - av.y;
            float cxa = av.x + 0.5f * wa, cya = av.y + 0.5f * ha;
            float dx = rv.x * 0.1f, dy = rv.y * 0.1f;
            float dw = rv.z * 0.2f, dh = rv.w * 0.2f;
            float pcx = cxa + dx * wa, pcy = cya + dy * ha;
            float pw = expf(dw) * wa, ph = expf(dh) * ha;
            float4 b;
            b.x = fmaxf(pcx - 0.5f * pw, 0.0f);
            b.y = fmaxf(pcy - 0.5f * ph, 0.0f);
            b.z = fminf(pcx + 0.5f * pw, IMGW);
            b.w = fminf(pcy + 0.5f * ph, IMGH);
            bx[rk] = b;
            bar[rk] = fmaxf(b.z - b.x, 0.0f) * fmaxf(b.w - b.y, 0.0f);
            ssc[rk] = __uint_as_float((unsigned int)(ke >> 32));
        }
    }
    __syncthreads();

    // ---- parallel intra-chunk 64x64 suppression bit-matrices ----
    for (int r = wid; r < meff; r += 16) {
        float4 bi = bx[r];
        float ai = bar[r];
        int col = (r & ~63) | lane;
        bool pred = false;
        if (col > r && col < meff) {
            float4 bj = bx[col];
            float aj = bar[col];
            float xx1 = fmaxf(bi.x, bj.x), yy1 = fmaxf(bi.y, bj.y);
            float xx2 = fminf(bi.z, bj.z), yy2 = fminf(bi.w, bj.w);
            float inter = fmaxf(xx2 - xx1, 0.0f) * fmaxf(yy2 - yy1, 0.0f);
            float uni = (ai + aj) - inter;
            pred = (inter / fmaxf(uni, 1e-8f)) > IOUT;
        }
        u64 m = __ballot(pred);
        if (lane == 0) intra[r] = m;
    }
    __syncthreads();

    // ---- own rows for the apply phase (registers) ----
    int j0 = tid, j1 = tid + 1024;
    float4 ob0 = make_float4(0, 0, 0, 0), ob1 = make_float4(0, 0, 0, 0);
    float oa0 = 0, oa1 = 0;
    if (j0 < meff) { ob0 = bx[j0]; oa0 = bar[j0]; }
    if (j1 < meff) { ob1 = bx[j1]; oa1 = bar[j1]; }
    bool done0 = (j0 >= meff), done1 = (j1 >= meff);

    int nchunk = (meff + 63) >> 6;
    for (int t = 0; t < nchunk; ++t) {
        int base = t << 6;
        if (wid == 0) {
            // serial greedy on bitmasks only; iterations == kept count
            int r = base + lane;
            bool valid = (r < meff) && (sup[r] == 0);
            u64 pending = __ballot(valid);
            u64 mr = (r < meff) ? intra[r] : 0ULL;
            unsigned int mlo = (unsigned int)mr;
            unsigned int mhi = (unsigned int)(mr >> 32);
            u64 kept = 0;
            while (pending) {
                int b = __ffsll(pending) - 1;
                kept |= 1ULL << b;
                unsigned int lo = (unsigned int)__builtin_amdgcn_readlane((int)mlo, b);
                unsigned int hi = (unsigned int)__builtin_amdgcn_readlane((int)mhi, b);
                u64 sm = (((u64)hi << 32) | lo) | (1ULL << b);
                pending &= ~sm;
            }
            if (valid && !((kept >> lane) & 1ULL)) sup[r] = 1;
            if (lane == 0) kept_sh = kept;
        }
        __syncthreads();

        u64 kb = kept_sh;
        int lim = base + 64;
        if (!done0 && j0 < lim) done0 = true;   // own chunk now resolved
        if (!done1 && j1 < lim) done1 = true;
        if (kb && (!done0 || !done1)) {
            u64 bits = kb;
            while (bits) {
                int b = __ffsll(bits) - 1;
                bits &= bits - 1;
                int r = base + b;
                float4 pb = bx[r];     // broadcast LDS read
                float pa = bar[r];
                if (!done0) {
                    float xx1 = fmaxf(ob0.x, pb.x), yy1 = fmaxf(ob0.y, pb.y);
                    float xx2 = fminf(ob0.z, pb.z), yy2 = fminf(ob0.w, pb.w);
                    float inter = fmaxf(xx2 - xx1, 0.0f) * fmaxf(yy2 - yy1, 0.0f);
                    float uni = (oa0 + pa) - inter;
                    if (inter / fmaxf(uni, 1e-8f) > IOUT) { sup[j0] = 1; done0 = true; }
                }
                if (!done1) {
                    float xx1 = fmaxf(ob1.x, pb.x), yy1 = fmaxf(ob1.y, pb.y);
                    float xx2 = fminf(ob1.z, pb.z), yy2 = fminf(ob1.w, pb.w);
                    float inter = fmaxf(xx2 - xx1, 0.0f) * fmaxf(yy2 - yy1, 0.0f);
                    float uni = (oa1 + pa) - inter;
                    if (inter / fmaxf(uni, 1e-8f) > IOUT) { sup[j1] = 1; done1 = true; }
                }
            }
        }
        __syncthreads();
    }

    // ---- write all NK rows for this class (kept -> data, else zeros) ----
    for (int r = tid; r < NK; r += 1024) {
        int row = c * NK + r;
        bool k = (r < meff) && (sup[r] == 0);
        float x1 = 0, y1 = 0, x2 = 0, y2 = 0, s = 0, cl = 0;
        if (k) {
            float4 b = bx[r];
            x1 = b.x; y1 = b.y; x2 = b.z; y2 = b.w;
            s = ssc[r]; cl = (float)c;
        }
        out[row * 6 + 0] = x1;
        out[row * 6 + 1] = y1;
        out[row * 6 + 2] = x2;
        out[row * 6 + 3] = y2;
        out[row * 6 + 4] = s;
        out[row * 6 + 5] = cl;
    }
}

extern "C" void kernel_launch(void* const* d_in, const int* in_sizes, int n_in,
                              void* d_out, int out_size, void* d_ws, size_t ws_size,
                              hipStream_t stream) {
    const float* cls = (const float*)d_in[0];   // [1, A, C]
    const float4* reg = (const float4*)d_in[1]; // [1, A, 4]
    const float4* anc = (const float4*)d_in[2]; // [1, A, 4]
    float* out = (float*)d_out;                 // [C*K, 6]

    char* ws = (char*)d_ws;
    int* counts = (int*)(ws + 0);
    u64* vkey = (u64*)(ws + 1024);

    k_init<<<1, NC * CSTRIDE, 0, stream>>>(counts);
    k_scan<<<NA / 1024, 1024, 0, stream>>>(cls, counts, vkey);
    k_rank_nms<<<NC, 1024, 0, stream>>>(counts, vkey, anc, reg, out);
}

// Round 5
// 208.595 us; speedup vs baseline: 3.3505x; 1.6793x over previous
//
#include <hip/hip_runtime.h>

#pragma clang fp contract(off)

#define NA 131072
#define NC 8
#define NK 2048
#define CAP 8192
#define NW 32          // 64-bit words per mask row
#define CONF 0.99f
#define IOUT 0.5f
#define IMGW 320.0f
#define IMGH 256.0f
#define CSTRIDE 32     // ints between class counters (separate cachelines)

typedef unsigned long long u64;

// ---------------- ws layout (bytes) ----------------
// counts : NC*CSTRIDE int @ 0        (1,024)
// vkey   : NC*CAP u64     @ 1024     (524,288)
// sbox   : NC*NK float4   @ 525312   (262,144)
// sar    : NC*NK float    @ 787456   (65,536)
// ssc    : NC*NK float    @ 852992   (65,536)
// mask   : NC*NK*NW u64   @ 918528   (4,194,304)   total ~5.1 MB

// Exact-decision IoU > 0.5 without (usually) dividing:
// fast: diff = inter - 0.5*uni  (0.5*uni exact; subtraction exact near thr)
// fall back to the correctly-rounded division only in the ambiguity band.
__device__ __forceinline__ bool iou_gt(float bix, float biy, float biz, float biw, float ai,
                                       float bjx, float bjy, float bjz, float bjw, float aj) {
    float xx1 = fmaxf(bix, bjx), yy1 = fmaxf(biy, bjy);
    float xx2 = fminf(biz, bjz), yy2 = fminf(biw, bjw);
    float inter = fmaxf(xx2 - xx1, 0.0f) * fmaxf(yy2 - yy1, 0.0f);
    float uni = (ai + aj) - inter;
    float th = 0.5f * uni;
    float diff = inter - th;
    bool pred = diff > 0.0f;
    if (__builtin_expect((uni < 1e-8f) || (pred && diff < th * 1e-6f), 0)) {
        pred = (inter / fmaxf(uni, 1e-8f)) > IOUT;
    }
    return pred;
}

// score scan + compaction into per-class key arrays.
// key = (score_bits << 32) | ~anchor  -> desc key == (score desc, idx asc)
__global__ __launch_bounds__(1024) void k_scan(const float* __restrict__ cls,
                                               int* __restrict__ counts,
                                               u64* __restrict__ vkey) {
    __shared__ int lcnt[NC];
    __shared__ int lbase[NC];
    int tid = threadIdx.x;
    int lane = tid & 63;
    int a = blockIdx.x * 1024 + tid;

    const float4* c4 = (const float4*)(cls + (size_t)a * NC);
    float4 s0 = c4[0], s1 = c4[1];
    float sc[8] = {s0.x, s0.y, s0.z, s0.w, s1.x, s1.y, s1.z, s1.w};

    if (tid < NC) lcnt[tid] = 0;
    __syncthreads();

    int wbase[NC], off[NC];
    bool hit[NC];
    #pragma unroll
    for (int c = 0; c < NC; ++c) {
        float s = sc[c];
        bool p = s > CONF;
        u64 m = __ballot(p);
        int cnt = __popcll(m);
        int wb = 0;
        if (cnt && lane == 0) wb = atomicAdd(&lcnt[c], cnt);
        wb = __shfl(wb, 0);
        wbase[c] = wb;
        hit[c] = p;
        off[c] = __popcll(m & ((1ULL << lane) - 1ULL));
    }
    __syncthreads();
    if (tid < NC) lbase[tid] = atomicAdd(&counts[tid * CSTRIDE], lcnt[tid]);
    __syncthreads();

    #pragma unroll
    for (int c = 0; c < NC; ++c) {
        if (hit[c]) {
            int pos = lbase[c] + wbase[c] + off[c];
            if (pos < CAP) {
                vkey[c * CAP + pos] =
                    ((u64)__float_as_uint(sc[c]) << 32) | (unsigned int)(~a);
            }
        }
    }
}

// rank-by-count (readlane tiles) + lazy decode into sorted slots (global).
__global__ __launch_bounds__(1024) void k_rank(const int* __restrict__ counts,
                                               const u64* __restrict__ vkey,
                                               const float4* __restrict__ anc,
                                               const float4* __restrict__ reg,
                                               float4* __restrict__ sbox,
                                               float* __restrict__ sar,
                                               float* __restrict__ ssc) {
    __shared__ u64 kv[CAP];
    int c = blockIdx.y;
    int tid = threadIdx.x, lane = tid & 63;
    int M = min(counts[c * CSTRIDE], CAP);
    if (blockIdx.x * 1024 >= M) return;   // uniform: before any barrier
    int Mr = (M + 63) & ~63;
    for (int i = tid; i < Mr; i += 1024) kv[i] = (i < M) ? vkey[c * CAP + i] : 0ULL;
    __syncthreads();

    int e = blockIdx.x * 1024 + tid;
    u64 ke = (e < M) ? kv[e] : ~0ULL;
    int rank = 0;
    if (__any(e < M)) {
        for (int base = 0; base < Mr; base += 64) {
            u64 tile = kv[base + lane];
            unsigned tlo = (unsigned)tile, thi = (unsigned)(tile >> 32);
            #pragma unroll
            for (int b = 0; b < 64; ++b) {
                unsigned lo = (unsigned)__builtin_amdgcn_readlane((int)tlo, b);
                unsigned hi = (unsigned)__builtin_amdgcn_readlane((int)thi, b);
                u64 key = ((u64)hi << 32) | lo;
                rank += (key > ke);
            }
        }
    }
    if (e < M && rank < NK) {
        int idx = (int)(~(unsigned int)ke);
        float4 av = anc[idx];
        float4 rv = reg[idx];
        float wa = av.z - av.x, ha = av.w - av.y;
        float cxa = av.x + 0.5f * wa, cya = av.y + 0.5f * ha;
        float dx = rv.x * 0.1f, dy = rv.y * 0.1f;
        float dw = rv.z * 0.2f, dh = rv.w * 0.2f;
        float pcx = cxa + dx * wa, pcy = cya + dy * ha;
        float pw = expf(dw) * wa, ph = expf(dh) * ha;
        float4 b;
        b.x = fmaxf(pcx - 0.5f * pw, 0.0f);
        b.y = fmaxf(pcy - 0.5f * ph, 0.0f);
        b.z = fminf(pcx + 0.5f * pw, IMGW);
        b.w = fminf(pcy + 0.5f * ph, IMGH);
        sbox[c * NK + rank] = b;
        sar[c * NK + rank] = fmaxf(b.z - b.x, 0.0f) * fmaxf(b.w - b.y, 0.0f);
        ssc[c * NK + rank] = __uint_as_float((unsigned int)(ke >> 32));
    }
}

// full suppression bit-matrix, words >= own chunk. grid (32, NC) = 256 blocks.
__global__ __launch_bounds__(1024) void k_mask(const int* __restrict__ counts,
                                               const float4* __restrict__ sbox,
                                               const float* __restrict__ sar,
                                               u64* __restrict__ mask) {
    __shared__ float4 bx[NK];
    __shared__ float ba[NK];
    int c = blockIdx.y, t = blockIdx.x;
    int meff = min(min(counts[c * CSTRIDE], CAP), NK);
    if (t * 64 >= meff) return;   // uniform: before any barrier
    int tid = threadIdx.x, lane = tid & 63, wid = tid >> 6;
    for (int r = tid; r < meff; r += 1024) {
        bx[r] = sbox[c * NK + r];
        ba[r] = sar[c * NK + r];
    }
    __syncthreads();
    #pragma unroll
    for (int k = 0; k < 4; ++k) {
        int r = t * 64 + wid * 4 + k;       // uniform per wave
        if (r >= meff) break;
        float4 bi = bx[r];
        float ai = ba[r];
        for (int W = t; W < NW; ++W) {
            int col = W * 64 + lane;
            bool pred = false;
            if (col > r && col < meff) {
                float4 bj = bx[col];
                pred = iou_gt(bi.x, bi.y, bi.z, bi.w, ai,
                              bj.x, bj.y, bj.z, bj.w, ba[col]);
            }
            u64 m = __ballot(pred);
            if (lane == 0) mask[((size_t)(c * NK + r)) * NW + W] = m;
        }
    }
}

// per-class merge: bitmask greedy (prefetched diagonal) + speculative
// pipelined mask-row OR apply + output write. grid NC x 256 threads.
__global__ __launch_bounds__(256) void k_merge(const int* __restrict__ counts,
                                               const float4* __restrict__ sbox,
                                               const float* __restrict__ ssc,
                                               const u64* __restrict__ mask,
                                               float* __restrict__ out) {
    __shared__ u64 remv[NW];
    __shared__ u64 keptw[NW];
    __shared__ int vlist[64];
    __shared__ int vcnt_sh;
    __shared__ u64 ortmp[8][NW];
    int c = blockIdx.x;
    int tid = threadIdx.x, lane = tid & 63, wid = tid >> 6;
    int meff = min(min(counts[c * CSTRIDE], CAP), NK);
    int nchunk = (meff + 63) >> 6;
    for (int i = tid; i < NW; i += 256) { remv[i] = 0ULL; keptw[i] = 0ULL; }
    __syncthreads();

    int w = tid & 31, k8 = tid >> 5;
    u64 diag_pref = 0ULL;
    if (wid == 0 && nchunk > 0)
        diag_pref = mask[((size_t)(c * NK + lane)) * NW + 0];

    for (int t = 0; t < nchunk; ++t) {
        u64 pending = 0ULL;
        if (wid == 0) {
            int r = t * 64 + lane;
            bool valid = (r < meff) && !((remv[t] >> lane) & 1ULL);
            u64 vm = __ballot(valid);
            if (valid) vlist[__popcll(vm & ((1ULL << lane) - 1ULL))] = r;
            if (lane == 0) vcnt_sh = (int)__popcll(vm);
            pending = vm;
        }
        __syncthreads();
        int vcnt = vcnt_sh;

        // speculative loads for all valid rows' words (> t): independent, pipelined
        u64 spec[8];
        #pragma unroll
        for (int q = 0; q < 8; ++q) {
            int k = k8 + q * 8;
            spec[q] = (w > t && k < vcnt)
                      ? mask[((size_t)(c * NK + vlist[k])) * NW + w] : 0ULL;
        }

        if (wid == 0) {
            u64 cur = diag_pref;
            if (t + 1 < nchunk)
                diag_pref = mask[((size_t)(c * NK + (t + 1) * 64 + lane)) * NW + (t + 1)];
            unsigned clo = (unsigned)cur, chi = (unsigned)(cur >> 32);
            u64 kept = 0ULL;
            while (pending) {
                int b = __ffsll(pending) - 1;
                kept |= 1ULL << b;
                unsigned lo = (unsigned)__builtin_amdgcn_readlane((int)clo, b);
                unsigned hi = (unsigned)__builtin_amdgcn_readlane((int)chi, b);
                u64 sm = (((u64)hi << 32) | lo) | (1ULL << b);
                pending &= ~sm;
            }
            if (lane == 0) keptw[t] = kept;
        }
        __syncthreads();

        u64 kept = keptw[t];
        u64 acc = 0ULL;
        #pragma unroll
        for (int q = 0; q < 8; ++q) {
            int k = k8 + q * 8;
            if (k < vcnt) {
                int rr = vlist[k];
                if ((kept >> (rr & 63)) & 1ULL) acc |= spec[q];
            }
        }
        ortmp[k8][w] = acc;
        __syncthreads();
        if (tid < NW) {
            u64 o = remv[tid];
            #pragma unroll
            for (int q = 0; q < 8; ++q) o |= ortmp[q][tid];
            remv[tid] = o;
        }
        __syncthreads();
    }

    // write all NK rows (kept -> data, else zeros)
    for (int r = tid; r < NK; r += 256) {
        bool kp = (r < meff) && ((keptw[r >> 6] >> (r & 63)) & 1ULL);
        float4 b = make_float4(0.0f, 0.0f, 0.0f, 0.0f);
        float s = 0.0f, cl = 0.0f;
        if (kp) {
            b = sbox[c * NK + r];
            s = ssc[c * NK + r];
            cl = (float)c;
        }
        int o = (c * NK + r) * 6;
        out[o + 0] = b.x;
        out[o + 1] = b.y;
        out[o + 2] = b.z;
        out[o + 3] = b.w;
        out[o + 4] = s;
        out[o + 5] = cl;
    }
}

extern "C" void kernel_launch(void* const* d_in, const int* in_sizes, int n_in,
                              void* d_out, int out_size, void* d_ws, size_t ws_size,
                              hipStream_t stream) {
    const float* cls = (const float*)d_in[0];   // [1, A, C]
    const float4* reg = (const float4*)d_in[1]; // [1, A, 4]
    const float4* anc = (const float4*)d_in[2]; // [1, A, 4]
    float* out = (float*)d_out;                 // [C*K, 6]

    char* ws = (char*)d_ws;
    int* counts = (int*)(ws + 0);
    u64* vkey = (u64*)(ws + 1024);
    float4* sbox = (float4*)(ws + 525312);
    float* sar = (float*)(ws + 787456);
    float* ssc = (float*)(ws + 852992);
    u64* mask = (u64*)(ws + 918528);

    hipMemsetAsync(counts, 0, NC * CSTRIDE * sizeof(int), stream);
    k_scan<<<NA / 1024, 1024, 0, stream>>>(cls, counts, vkey);
    k_rank<<<dim3(CAP / 1024, NC), 1024, 0, stream>>>(counts, vkey, anc, reg, sbox, sar, ssc);
    k_mask<<<dim3(NW, NC), 1024, 0, stream>>>(counts, sbox, sar, mask);
    k_merge<<<NC, 256, 0, stream>>>(counts, sbox, ssc, mask, out);
}